// Round 1
// baseline (442.537 us; speedup 1.0000x reference)
//
#include <hip/hip_runtime.h>
#include <cmath>

// GPTNeoXRoutedMLP: S=1024,B=2 -> N=2048 tokens, H=1024, F=4096, E=8, topk=2.
// Sparse dispatch (top-2 only) = 1/4 the dense reference FLOPs.
//
// ws layout:
//   [0, 256)      int meta[64]: [0..7]=counts, [8..16]=padded offsets (9), rest unused
//   [4096, ...)   int   topk_e[4096]
//   [20480,...)   float topk_s[4096]
//   [36864,...)   int   slot_token[5120]
//   [57344,...)   float slot_score[5120]
//   [1MB, 1MB+40MB) ushort h[5120][4096] (bf16)
// Total ws needed: ~43 MB.

#define H_DIM 1024
#define F_DIM 4096
#define E_NUM 8
#define N_TOK 2048
#define BM 128
#define BN 128
#define BK 64
#define LDT 72          // LDS row stride (bf16 elems): 64 + 8 pad -> breaks bank conflicts
#define MAX_SLOTS 5120  // 4096 assignments + 8*128 max padding
#define MAX_MT (MAX_SLOTS / BM)

typedef short s16x8 __attribute__((ext_vector_type(8)));
typedef float f32x4 __attribute__((ext_vector_type(4)));

__device__ __forceinline__ unsigned short f2bf(float f) {
  unsigned int u = __float_as_uint(f);
  u += 0x7fffu + ((u >> 16) & 1u);   // round-to-nearest-even
  return (unsigned short)(u >> 16);
}

// ---------------- Router: logits = x @ rw, top-2, softmax over top-2 ----------------
__global__ __launch_bounds__(64) void router_k(
    const float* __restrict__ x, const float* __restrict__ rw,
    int* __restrict__ meta, int* __restrict__ topk_e, float* __restrict__ topk_s) {
  const int n = blockIdx.x;
  const int l = threadIdx.x;
  float part[E_NUM];
#pragma unroll
  for (int e = 0; e < E_NUM; ++e) part[e] = 0.f;
  const float* xr = x + (size_t)n * H_DIM;
  for (int h = l; h < H_DIM; h += 64) {
    const float xv = xr[h];
    const float* rwr = rw + h * E_NUM;
#pragma unroll
    for (int e = 0; e < E_NUM; ++e) part[e] += xv * rwr[e];
  }
#pragma unroll
  for (int e = 0; e < E_NUM; ++e) {
#pragma unroll
    for (int off = 32; off > 0; off >>= 1) part[e] += __shfl_down(part[e], off);
  }
  if (l == 0) {
    float v0 = -3.4e38f, v1 = -3.4e38f;
    int i0 = 0, i1 = 0;
#pragma unroll
    for (int e = 0; e < E_NUM; ++e) {
      float v = part[e];
      if (v > v0) { v1 = v0; i1 = i0; v0 = v; i0 = e; }  // strict > : ties -> lowest index (matches lax.top_k)
      else if (v > v1) { v1 = v; i1 = e; }
    }
    const float e1 = expf(v1 - v0);
    const float inv = 1.f / (1.f + e1);
    topk_e[2 * n] = i0; topk_e[2 * n + 1] = i1;
    topk_s[2 * n] = inv; topk_s[2 * n + 1] = e1 * inv;
    atomicAdd(&meta[i0], 1);
    atomicAdd(&meta[i1], 1);
  }
}

// ------------- Scatter: padded offsets + permuted slot lists (one block) -------------
__global__ __launch_bounds__(256) void scatter_k(
    int* __restrict__ meta, const int* __restrict__ topk_e,
    const float* __restrict__ topk_s, int* __restrict__ slot_token,
    float* __restrict__ slot_score) {
  __shared__ int soff[9];
  __shared__ int scur[8];
  const int t = threadIdx.x;
  if (t == 0) {
    int acc = 0;
    for (int e = 0; e < E_NUM; ++e) {
      soff[e] = acc;
      meta[8 + e] = acc;
      acc += ((meta[e] + BM - 1) / BM) * BM;  // pad each expert range to tile multiple
    }
    soff[8] = acc;
    meta[16] = acc;
  }
  if (t < 8) scur[t] = 0;
  __syncthreads();
  for (int i = t; i < MAX_SLOTS; i += 256) slot_token[i] = -1;
  __syncthreads();
  for (int a = t; a < N_TOK * 2; a += 256) {
    const int e = topk_e[a];
    const int pos = atomicAdd(&scur[e], 1);
    const int slot = soff[e] + pos;
    slot_token[slot] = a >> 1;
    slot_score[slot] = topk_s[a];
  }
}

// ---------------- GEMM1: h = gelu(x[gather] @ w1[e] + b1[e]), bf16 out ----------------
__global__ __launch_bounds__(256) void gemm1_k(
    const float* __restrict__ x, const float* __restrict__ w1,
    const float* __restrict__ b1, const int* __restrict__ meta,
    const int* __restrict__ slot_token, unsigned short* __restrict__ hbuf) {
  __shared__ unsigned short Al[BM * LDT];
  __shared__ unsigned short Bl[BN * LDT];
  const int m0 = blockIdx.x * BM;
  const int total = meta[16];
  if (m0 >= total) return;
  int exp = 0;
#pragma unroll
  for (int e = 1; e < E_NUM; ++e) if (m0 >= meta[8 + e]) exp = e;
  const int n0 = blockIdx.y * BN;
  const int t = threadIdx.x;
  const int w = t >> 6, l = t & 63;
  const int wm = w >> 1, wn = w & 1;
  const int lr = l & 15, lg = l >> 4;

  const f32x4 fzero = {0.f, 0.f, 0.f, 0.f};
  f32x4 acc[4][4];
#pragma unroll
  for (int a = 0; a < 4; ++a)
#pragma unroll
    for (int b = 0; b < 4; ++b) acc[a][b] = fzero;

  // A staging: 2 threads per row, 8 float4 each (gather via slot_token)
  const int ar = t >> 1, ah = t & 1;
  const int tokA = slot_token[m0 + ar];
  const float* xrow = (tokA >= 0) ? (x + (size_t)tokA * H_DIM + ah * 32) : x;
  // B staging: micro-transpose, thread covers col group (t&31)*4, k groups (t>>5) and (t>>5)+8
  const size_t wbase = (size_t)exp * H_DIM * F_DIM;
  const int cg4 = (t & 31) * 4;
  const int kg0 = t >> 5;

  for (int kt = 0; kt < H_DIM / BK; ++kt) {
    const int k0 = kt * BK;
    __syncthreads();
    {
      const float* xp = xrow + k0;
#pragma unroll
      for (int i = 0; i < 8; ++i) {
        f32x4 v = fzero;
        if (tokA >= 0) v = *(const f32x4*)(xp + i * 4);
        ushort4 u;
        u.x = f2bf(v[0]); u.y = f2bf(v[1]); u.z = f2bf(v[2]); u.w = f2bf(v[3]);
        *(ushort4*)&Al[ar * LDT + ah * 32 + i * 4] = u;
      }
    }
#pragma unroll
    for (int half = 0; half < 2; ++half) {
      const int kg = kg0 + half * 8;
      const float* wp = w1 + wbase + (size_t)(k0 + kg * 4) * F_DIM + n0 + cg4;
      f32x4 r0 = *(const f32x4*)(wp);
      f32x4 r1 = *(const f32x4*)(wp + F_DIM);
      f32x4 r2 = *(const f32x4*)(wp + 2 * F_DIM);
      f32x4 r3 = *(const f32x4*)(wp + 3 * F_DIM);
#pragma unroll
      for (int cc = 0; cc < 4; ++cc) {
        ushort4 u;
        u.x = f2bf(r0[cc]); u.y = f2bf(r1[cc]); u.z = f2bf(r2[cc]); u.w = f2bf(r3[cc]);
        *(ushort4*)&Bl[(cg4 + cc) * LDT + kg * 4] = u;   // B^T in LDS: [col][k]
      }
    }
    __syncthreads();
#pragma unroll
    for (int kk = 0; kk < 2; ++kk) {
      s16x8 af[4], bb[4];
#pragma unroll
      for (int fm = 0; fm < 4; ++fm)
        af[fm] = *(const s16x8*)&Al[(wm * 64 + fm * 16 + lr) * LDT + kk * 32 + lg * 8];
#pragma unroll
      for (int fn = 0; fn < 4; ++fn)
        bb[fn] = *(const s16x8*)&Bl[(wn * 64 + fn * 16 + lr) * LDT + kk * 32 + lg * 8];
#pragma unroll
      for (int fm = 0; fm < 4; ++fm)
#pragma unroll
        for (int fn = 0; fn < 4; ++fn)
          acc[fm][fn] = __builtin_amdgcn_mfma_f32_16x16x32_bf16(af[fm], bb[fn], acc[fm][fn], 0, 0, 0);
    }
  }
  // epilogue: + b1, exact gelu, store bf16
#pragma unroll
  for (int fn = 0; fn < 4; ++fn) {
    const int col = n0 + wn * 64 + fn * 16 + lr;
    const float bias = b1[exp * F_DIM + col];
#pragma unroll
    for (int fm = 0; fm < 4; ++fm) {
      const int rbase = m0 + wm * 64 + fm * 16 + lg * 4;
#pragma unroll
      for (int i = 0; i < 4; ++i) {
        const float v = acc[fm][fn][i] + bias;
        const float g = 0.5f * v * (1.f + erff(v * 0.70710678118f));
        hbuf[(size_t)(rbase + i) * F_DIM + col] = f2bf(g);
      }
    }
  }
}

// ------- GEMM2: y = h @ w2[e]; out[token] += score*(y + b2[e]) (atomic combine) -------
__global__ __launch_bounds__(256) void gemm2_k(
    const unsigned short* __restrict__ hbuf, const float* __restrict__ w2,
    const float* __restrict__ b2, const int* __restrict__ meta,
    const int* __restrict__ slot_token, const float* __restrict__ slot_score,
    float* __restrict__ out) {
  __shared__ unsigned short Al[BM * LDT];
  __shared__ unsigned short Bl[BN * LDT];
  const int m0 = blockIdx.x * BM;
  const int total = meta[16];
  if (m0 >= total) return;
  int exp = 0;
#pragma unroll
  for (int e = 1; e < E_NUM; ++e) if (m0 >= meta[8 + e]) exp = e;
  const int n0 = blockIdx.y * BN;
  const int t = threadIdx.x;
  const int w = t >> 6, l = t & 63;
  const int wm = w >> 1, wn = w & 1;
  const int lr = l & 15, lg = l >> 4;

  const f32x4 fzero = {0.f, 0.f, 0.f, 0.f};
  f32x4 acc[4][4];
#pragma unroll
  for (int a = 0; a < 4; ++a)
#pragma unroll
    for (int b = 0; b < 4; ++b) acc[a][b] = fzero;

  const int ar = t >> 1, ah = t & 1;
  const unsigned short* hrow = hbuf + (size_t)(m0 + ar) * F_DIM + ah * 32;
  const size_t wbase = (size_t)exp * F_DIM * H_DIM;
  const int cg4 = (t & 31) * 4;
  const int kg0 = t >> 5;

  for (int kt = 0; kt < F_DIM / BK; ++kt) {
    const int k0 = kt * BK;
    __syncthreads();
#pragma unroll
    for (int i = 0; i < 4; ++i) {  // h already bf16: straight 16B copies
      *(int4*)&Al[ar * LDT + ah * 32 + i * 8] = *(const int4*)(hrow + k0 + i * 8);
    }
#pragma unroll
    for (int half = 0; half < 2; ++half) {
      const int kg = kg0 + half * 8;
      const float* wp = w2 + wbase + (size_t)(k0 + kg * 4) * H_DIM + n0 + cg4;
      f32x4 r0 = *(const f32x4*)(wp);
      f32x4 r1 = *(const f32x4*)(wp + H_DIM);
      f32x4 r2 = *(const f32x4*)(wp + 2 * H_DIM);
      f32x4 r3 = *(const f32x4*)(wp + 3 * H_DIM);
#pragma unroll
      for (int cc = 0; cc < 4; ++cc) {
        ushort4 u;
        u.x = f2bf(r0[cc]); u.y = f2bf(r1[cc]); u.z = f2bf(r2[cc]); u.w = f2bf(r3[cc]);
        *(ushort4*)&Bl[(cg4 + cc) * LDT + kg * 4] = u;
      }
    }
    __syncthreads();
#pragma unroll
    for (int kk = 0; kk < 2; ++kk) {
      s16x8 af[4], bb[4];
#pragma unroll
      for (int fm = 0; fm < 4; ++fm)
        af[fm] = *(const s16x8*)&Al[(wm * 64 + fm * 16 + lr) * LDT + kk * 32 + lg * 8];
#pragma unroll
      for (int fn = 0; fn < 4; ++fn)
        bb[fn] = *(const s16x8*)&Bl[(wn * 64 + fn * 16 + lr) * LDT + kk * 32 + lg * 8];
#pragma unroll
      for (int fm = 0; fm < 4; ++fm)
#pragma unroll
        for (int fn = 0; fn < 4; ++fn)
          acc[fm][fn] = __builtin_amdgcn_mfma_f32_16x16x32_bf16(af[fm], bb[fn], acc[fm][fn], 0, 0, 0);
    }
  }
  // epilogue: out[token] += s * (y + b2). Exactly 2 commutative f32 adds per element.
#pragma unroll
  for (int fm = 0; fm < 4; ++fm) {
    const int rbase = m0 + wm * 64 + fm * 16 + lg * 4;
    int toks[4]; float ss[4];
#pragma unroll
    for (int i = 0; i < 4; ++i) {
      toks[i] = slot_token[rbase + i];
      ss[i] = slot_score[rbase + i];
    }
#pragma unroll
    for (int fn = 0; fn < 4; ++fn) {
      const int col = n0 + wn * 64 + fn * 16 + lr;
      const float b2v = b2[exp * H_DIM + col];
#pragma unroll
      for (int i = 0; i < 4; ++i) {
        if (toks[i] >= 0)
          atomicAdd(out + (size_t)toks[i] * H_DIM + col, ss[i] * (acc[fm][fn][i] + b2v));
      }
    }
  }
}

extern "C" void kernel_launch(void* const* d_in, const int* in_sizes, int n_in,
                              void* d_out, int out_size, void* d_ws, size_t ws_size,
                              hipStream_t stream) {
  const float* x  = (const float*)d_in[0];
  const float* rw = (const float*)d_in[1];
  const float* w1 = (const float*)d_in[2];
  const float* b1 = (const float*)d_in[3];
  const float* w2 = (const float*)d_in[4];
  const float* b2 = (const float*)d_in[5];
  float* out = (float*)d_out;
  char* ws = (char*)d_ws;

  int*   meta       = (int*)ws;
  int*   topk_e     = (int*)(ws + 4096);
  float* topk_s     = (float*)(ws + 20480);
  int*   slot_token = (int*)(ws + 36864);
  float* slot_score = (float*)(ws + 57344);
  unsigned short* hbuf = (unsigned short*)(ws + (1 << 20));

  hipMemsetAsync(meta, 0, 256, stream);
  hipMemsetAsync(out, 0, (size_t)N_TOK * H_DIM * sizeof(float), stream);

  router_k<<<N_TOK, 64, 0, stream>>>(x, rw, meta, topk_e, topk_s);
  scatter_k<<<1, 256, 0, stream>>>(meta, topk_e, topk_s, slot_token, slot_score);
  gemm1_k<<<dim3(MAX_MT, F_DIM / BN), 256, 0, stream>>>(x, w1, b1, meta, slot_token, hbuf);
  gemm2_k<<<dim3(MAX_MT, H_DIM / BN), 256, 0, stream>>>(hbuf, w2, b2, meta, slot_token, slot_score, out);
}

// Round 2
// 305.753 us; speedup vs baseline: 1.4474x; 1.4474x over previous
//
#include <hip/hip_runtime.h>
#include <cmath>

// GPTNeoXRoutedMLP: N=2048 tokens, H=1024, F=4096, E=8, topk=2.
// R2: pre-convert/transpose weights to bf16, m97-style GEMMs with
// global_load_lds(16B) + XOR-swizzled LDS, XCD-chunked block swizzle.

#define H_DIM 1024
#define F_DIM 4096
#define E_NUM 8
#define N_TOK 2048
#define BM 128
#define BK 64
#define LDT 72
#define MAX_SLOTS 5120
#define MAX_MT (MAX_SLOTS / BM)

typedef short s16x8 __attribute__((ext_vector_type(8)));
typedef float f32x4 __attribute__((ext_vector_type(4)));

__device__ __forceinline__ unsigned short f2bf(float f) {
  unsigned int u = __float_as_uint(f);
  u += 0x7fffu + ((u >> 16) & 1u);   // RNE
  return (unsigned short)(u >> 16);
}

__device__ __forceinline__ void gload_lds16(const void* g, void* l) {
  __builtin_amdgcn_global_load_lds(
      (const __attribute__((address_space(1))) unsigned int*)g,
      (__attribute__((address_space(3))) unsigned int*)l, 16, 0, 0);
}

__device__ __forceinline__ int xcd_swz(int orig, int nwg) {
  // nwg must be a multiple of 8 (it is: 1280 / 640)
  const int cpx = nwg >> 3;
  return (orig & 7) * cpx + (orig >> 3);
}

// ---------------- Router ----------------
__global__ __launch_bounds__(64) void router_k(
    const float* __restrict__ x, const float* __restrict__ rw,
    int* __restrict__ meta, int* __restrict__ topk_e, float* __restrict__ topk_s) {
  const int n = blockIdx.x;
  const int l = threadIdx.x;
  float part[E_NUM];
#pragma unroll
  for (int e = 0; e < E_NUM; ++e) part[e] = 0.f;
  const float* xr = x + (size_t)n * H_DIM;
  for (int h = l; h < H_DIM; h += 64) {
    const float xv = xr[h];
    const float* rwr = rw + h * E_NUM;
#pragma unroll
    for (int e = 0; e < E_NUM; ++e) part[e] += xv * rwr[e];
  }
#pragma unroll
  for (int e = 0; e < E_NUM; ++e) {
#pragma unroll
    for (int off = 32; off > 0; off >>= 1) part[e] += __shfl_down(part[e], off);
  }
  if (l == 0) {
    float v0 = -3.4e38f, v1 = -3.4e38f;
    int i0 = 0, i1 = 0;
#pragma unroll
    for (int e = 0; e < E_NUM; ++e) {
      float v = part[e];
      if (v > v0) { v1 = v0; i1 = i0; v0 = v; i0 = e; }
      else if (v > v1) { v1 = v; i1 = e; }
    }
    const float e1 = expf(v1 - v0);
    const float inv = 1.f / (1.f + e1);
    topk_e[2 * n] = i0; topk_e[2 * n + 1] = i1;
    topk_s[2 * n] = inv; topk_s[2 * n + 1] = e1 * inv;
    atomicAdd(&meta[i0], 1);
    atomicAdd(&meta[i1], 1);
  }
}

// ---------------- Scatter ----------------
__global__ __launch_bounds__(256) void scatter_k(
    int* __restrict__ meta, const int* __restrict__ topk_e,
    const float* __restrict__ topk_s, int* __restrict__ slot_token,
    float* __restrict__ slot_score) {
  __shared__ int soff[9];
  __shared__ int scur[8];
  const int t = threadIdx.x;
  if (t == 0) {
    int acc = 0;
    for (int e = 0; e < E_NUM; ++e) {
      soff[e] = acc;
      meta[8 + e] = acc;
      acc += ((meta[e] + BM - 1) / BM) * BM;
    }
    soff[8] = acc;
    meta[16] = acc;
  }
  if (t < 8) scur[t] = 0;
  __syncthreads();
  for (int i = t; i < MAX_SLOTS; i += 256) slot_token[i] = -1;
  __syncthreads();
  for (int a = t; a < N_TOK * 2; a += 256) {
    const int e = topk_e[a];
    const int pos = atomicAdd(&scur[e], 1);
    const int slot = soff[e] + pos;
    slot_token[slot] = a >> 1;
    slot_score[slot] = topk_s[a];
  }
}

// ---------------- x f32 -> bf16 ----------------
__global__ __launch_bounds__(256) void cvtx_k(const float* __restrict__ x,
                                              unsigned short* __restrict__ xb) {
  const size_t i = ((size_t)blockIdx.x * 256 + threadIdx.x) * 8;
  f32x4 a = *(const f32x4*)(x + i);
  f32x4 b = *(const f32x4*)(x + i + 4);
  s16x8 u;
#pragma unroll
  for (int j = 0; j < 4; ++j) { u[j] = (short)f2bf(a[j]); u[4 + j] = (short)f2bf(b[j]); }
  *(s16x8*)&xb[i] = u;
}

// ------------- transpose-convert: in [E][R][C] f32 -> out [E][C][R] bf16 -------------
__global__ __launch_bounds__(256) void tcvt_k(const float* __restrict__ in,
                                              unsigned short* __restrict__ out,
                                              int R, int C) {
  __shared__ float T[64][65];
  const size_t eb = (size_t)blockIdx.z * R * C;
  in += eb; out += eb;
  const int c0 = blockIdx.x * 64;
  const int r0 = blockIdx.y * 64;
  const int t = threadIdx.x;
  const int cb = (t & 15) * 4;
#pragma unroll
  for (int it = 0; it < 4; ++it) {
    const int rr = (t >> 4) + it * 16;
    f32x4 v = *(const f32x4*)(in + (size_t)(r0 + rr) * C + c0 + cb);
#pragma unroll
    for (int c = 0; c < 4; ++c) T[rr][cb + c] = v[c];
  }
  __syncthreads();
  const int cc = t >> 2;
  const int rb = (t & 3) * 16;
#pragma unroll
  for (int half = 0; half < 2; ++half) {
    s16x8 u;
#pragma unroll
    for (int j = 0; j < 8; ++j) u[j] = (short)f2bf(T[rb + half * 8 + j][cc]);
    *(s16x8*)&out[(size_t)(c0 + cc) * R + r0 + rb + half * 8] = u;
  }
}

// ============ fast GEMM1: h = gelu(xb[gather] @ w1t^T + b1), bf16 out ============
// A: [BM=128][BK=64] bf16 LDS, B: [BN=128][BK=64] bf16 LDS, XOR-swizzled chunks.
__global__ __launch_bounds__(256) void gemm1_f(
    const unsigned short* __restrict__ xb, const unsigned short* __restrict__ w1t,
    const float* __restrict__ b1, const int* __restrict__ meta,
    const int* __restrict__ slot_token, unsigned short* __restrict__ hbuf) {
  __shared__ __align__(16) unsigned short Al[128 * 64];
  __shared__ __align__(16) unsigned short Bl[128 * 64];
  const int total = meta[16];
  const int wgid = xcd_swz(blockIdx.x, MAX_MT * 32);
  const int mt = wgid >> 5, nt = wgid & 31;
  const int m0 = mt * 128;
  if (m0 >= total) return;
  int exp = 0;
#pragma unroll
  for (int e = 1; e < E_NUM; ++e) if (m0 >= meta[8 + e]) exp = e;
  const int n0 = nt * 128;
  const int t = threadIdx.x, w = t >> 6, l = t & 63;
  const int wm = w >> 1, wn = w & 1, lr = l & 15, lg = l >> 4;
  const int sr = l >> 3, sc = l & 7;

  const unsigned short* srcA[4];
  const unsigned short* srcB[4];
#pragma unroll
  for (int i = 0; i < 4; ++i) {
    const int r = (w * 4 + i) * 8 + sr;
    const int cd = sc ^ (r & 7);
    int tk = slot_token[m0 + r]; if (tk < 0) tk = 0;
    srcA[i] = xb + (size_t)tk * H_DIM + cd * 8;
    srcB[i] = w1t + ((size_t)exp * F_DIM + n0 + r) * H_DIM + cd * 8;
  }

  const f32x4 fzero = {0.f, 0.f, 0.f, 0.f};
  f32x4 acc[4][4];
#pragma unroll
  for (int a = 0; a < 4; ++a)
#pragma unroll
    for (int b = 0; b < 4; ++b) acc[a][b] = fzero;

  for (int kt = 0; kt < H_DIM / BK; ++kt) {
    const int k0 = kt * BK;
    __syncthreads();
#pragma unroll
    for (int i = 0; i < 4; ++i)
      gload_lds16(srcA[i] + k0, &Al[(w * 4 + i) * 512]);
#pragma unroll
    for (int i = 0; i < 4; ++i)
      gload_lds16(srcB[i] + k0, &Bl[(w * 4 + i) * 512]);
    __syncthreads();
#pragma unroll
    for (int kk = 0; kk < 2; ++kk) {
      s16x8 af[4], bb[4];
#pragma unroll
      for (int fm = 0; fm < 4; ++fm) {
        const int row = wm * 64 + fm * 16 + lr;
        af[fm] = *(const s16x8*)&Al[row * 64 + (((kk * 4 + lg) ^ (row & 7)) * 8)];
      }
#pragma unroll
      for (int fn = 0; fn < 4; ++fn) {
        const int row = wn * 64 + fn * 16 + lr;
        bb[fn] = *(const s16x8*)&Bl[row * 64 + (((kk * 4 + lg) ^ (row & 7)) * 8)];
      }
#pragma unroll
      for (int fm = 0; fm < 4; ++fm)
#pragma unroll
        for (int fn = 0; fn < 4; ++fn)
          acc[fm][fn] = __builtin_amdgcn_mfma_f32_16x16x32_bf16(af[fm], bb[fn], acc[fm][fn], 0, 0, 0);
    }
  }
#pragma unroll
  for (int fn = 0; fn < 4; ++fn) {
    const int col = n0 + wn * 64 + fn * 16 + lr;
    const float bias = b1[exp * F_DIM + col];
#pragma unroll
    for (int fm = 0; fm < 4; ++fm) {
      const int rbase = m0 + wm * 64 + fm * 16 + lg * 4;
#pragma unroll
      for (int i = 0; i < 4; ++i) {
        const float v = acc[fm][fn][i] + bias;
        const float g = 0.5f * v * (1.f + erff(v * 0.70710678118f));
        hbuf[(size_t)(rbase + i) * F_DIM + col] = f2bf(g);
      }
    }
  }
}

// ============ fast GEMM2: out[token] += s*(hbuf @ w2t^T + b2), BN=64 ============
__global__ __launch_bounds__(256) void gemm2_f(
    const unsigned short* __restrict__ hbuf, const unsigned short* __restrict__ w2t,
    const float* __restrict__ b2, const int* __restrict__ meta,
    const int* __restrict__ slot_token, const float* __restrict__ slot_score,
    float* __restrict__ out) {
  __shared__ __align__(16) unsigned short Al[128 * 64];
  __shared__ __align__(16) unsigned short Bl[64 * 64];
  const int total = meta[16];
  const int wgid = xcd_swz(blockIdx.x, MAX_MT * 16);
  const int mt = wgid >> 4, nt = wgid & 15;
  const int m0 = mt * 128;
  if (m0 >= total) return;
  int exp = 0;
#pragma unroll
  for (int e = 1; e < E_NUM; ++e) if (m0 >= meta[8 + e]) exp = e;
  const int n0 = nt * 64;
  const int t = threadIdx.x, w = t >> 6, l = t & 63;
  const int wm = w >> 1, wn = w & 1, lr = l & 15, lg = l >> 4;
  const int sr = l >> 3, sc = l & 7;

  const unsigned short* srcA[4];
  const unsigned short* srcB[2];
#pragma unroll
  for (int i = 0; i < 4; ++i) {
    const int r = (w * 4 + i) * 8 + sr;
    const int cd = sc ^ (r & 7);
    srcA[i] = hbuf + (size_t)(m0 + r) * F_DIM + cd * 8;
  }
#pragma unroll
  for (int i = 0; i < 2; ++i) {
    const int r = (w * 2 + i) * 8 + sr;
    const int cd = sc ^ (r & 7);
    srcB[i] = w2t + ((size_t)exp * H_DIM + n0 + r) * F_DIM + cd * 8;
  }

  const f32x4 fzero = {0.f, 0.f, 0.f, 0.f};
  f32x4 acc[4][2];
#pragma unroll
  for (int a = 0; a < 4; ++a)
#pragma unroll
    for (int b = 0; b < 2; ++b) acc[a][b] = fzero;

  for (int kt = 0; kt < F_DIM / BK; ++kt) {
    const int k0 = kt * BK;
    __syncthreads();
#pragma unroll
    for (int i = 0; i < 4; ++i)
      gload_lds16(srcA[i] + k0, &Al[(w * 4 + i) * 512]);
#pragma unroll
    for (int i = 0; i < 2; ++i)
      gload_lds16(srcB[i] + k0, &Bl[(w * 2 + i) * 512]);
    __syncthreads();
#pragma unroll
    for (int kk = 0; kk < 2; ++kk) {
      s16x8 af[4], bb[2];
#pragma unroll
      for (int fm = 0; fm < 4; ++fm) {
        const int row = wm * 64 + fm * 16 + lr;
        af[fm] = *(const s16x8*)&Al[row * 64 + (((kk * 4 + lg) ^ (row & 7)) * 8)];
      }
#pragma unroll
      for (int fn = 0; fn < 2; ++fn) {
        const int row = wn * 32 + fn * 16 + lr;
        bb[fn] = *(const s16x8*)&Bl[row * 64 + (((kk * 4 + lg) ^ (row & 7)) * 8)];
      }
#pragma unroll
      for (int fm = 0; fm < 4; ++fm)
#pragma unroll
        for (int fn = 0; fn < 2; ++fn)
          acc[fm][fn] = __builtin_amdgcn_mfma_f32_16x16x32_bf16(af[fm], bb[fn], acc[fm][fn], 0, 0, 0);
    }
  }
#pragma unroll
  for (int fm = 0; fm < 4; ++fm) {
    const int rbase = m0 + wm * 64 + fm * 16 + lg * 4;
    int toks[4]; float ss[4];
#pragma unroll
    for (int i = 0; i < 4; ++i) {
      toks[i] = slot_token[rbase + i];
      ss[i] = slot_score[rbase + i];
    }
#pragma unroll
    for (int fn = 0; fn < 2; ++fn) {
      const int col = n0 + wn * 32 + fn * 16 + lr;
      const float b2v = b2[exp * H_DIM + col];
#pragma unroll
      for (int i = 0; i < 4; ++i) {
        if (toks[i] >= 0)
          atomicAdd(out + (size_t)toks[i] * H_DIM + col, ss[i] * (acc[fm][fn][i] + b2v));
      }
    }
  }
}

// ================= fallback (R1) GEMMs, used only if ws too small =================
__global__ __launch_bounds__(256) void gemm1_k(
    const float* __restrict__ x, const float* __restrict__ w1,
    const float* __restrict__ b1, const int* __restrict__ meta,
    const int* __restrict__ slot_token, unsigned short* __restrict__ hbuf) {
  __shared__ unsigned short Al[BM * LDT];
  __shared__ unsigned short Bl[128 * LDT];
  const int m0 = blockIdx.x * BM;
  const int total = meta[16];
  if (m0 >= total) return;
  int exp = 0;
#pragma unroll
  for (int e = 1; e < E_NUM; ++e) if (m0 >= meta[8 + e]) exp = e;
  const int n0 = blockIdx.y * 128;
  const int t = threadIdx.x;
  const int w = t >> 6, l = t & 63;
  const int wm = w >> 1, wn = w & 1;
  const int lr = l & 15, lg = l >> 4;
  const f32x4 fzero = {0.f, 0.f, 0.f, 0.f};
  f32x4 acc[4][4];
#pragma unroll
  for (int a = 0; a < 4; ++a)
#pragma unroll
    for (int b = 0; b < 4; ++b) acc[a][b] = fzero;
  const int ar = t >> 1, ah = t & 1;
  const int tokA = slot_token[m0 + ar];
  const float* xrow = (tokA >= 0) ? (x + (size_t)tokA * H_DIM + ah * 32) : x;
  const size_t wbase = (size_t)exp * H_DIM * F_DIM;
  const int cg4 = (t & 31) * 4;
  const int kg0 = t >> 5;
  for (int kt = 0; kt < H_DIM / BK; ++kt) {
    const int k0 = kt * BK;
    __syncthreads();
    {
      const float* xp = xrow + k0;
#pragma unroll
      for (int i = 0; i < 8; ++i) {
        f32x4 v = fzero;
        if (tokA >= 0) v = *(const f32x4*)(xp + i * 4);
        ushort4 u;
        u.x = f2bf(v[0]); u.y = f2bf(v[1]); u.z = f2bf(v[2]); u.w = f2bf(v[3]);
        *(ushort4*)&Al[ar * LDT + ah * 32 + i * 4] = u;
      }
    }
#pragma unroll
    for (int half = 0; half < 2; ++half) {
      const int kg = kg0 + half * 8;
      const float* wp = w1 + wbase + (size_t)(k0 + kg * 4) * F_DIM + n0 + cg4;
      f32x4 r0 = *(const f32x4*)(wp);
      f32x4 r1 = *(const f32x4*)(wp + F_DIM);
      f32x4 r2 = *(const f32x4*)(wp + 2 * F_DIM);
      f32x4 r3 = *(const f32x4*)(wp + 3 * F_DIM);
#pragma unroll
      for (int cc = 0; cc < 4; ++cc) {
        ushort4 u;
        u.x = f2bf(r0[cc]); u.y = f2bf(r1[cc]); u.z = f2bf(r2[cc]); u.w = f2bf(r3[cc]);
        *(ushort4*)&Bl[(cg4 + cc) * LDT + kg * 4] = u;
      }
    }
    __syncthreads();
#pragma unroll
    for (int kk = 0; kk < 2; ++kk) {
      s16x8 af[4], bb[4];
#pragma unroll
      for (int fm = 0; fm < 4; ++fm)
        af[fm] = *(const s16x8*)&Al[(wm * 64 + fm * 16 + lr) * LDT + kk * 32 + lg * 8];
#pragma unroll
      for (int fn = 0; fn < 4; ++fn)
        bb[fn] = *(const s16x8*)&Bl[(wn * 64 + fn * 16 + lr) * LDT + kk * 32 + lg * 8];
#pragma unroll
      for (int fm = 0; fm < 4; ++fm)
#pragma unroll
        for (int fn = 0; fn < 4; ++fn)
          acc[fm][fn] = __builtin_amdgcn_mfma_f32_16x16x32_bf16(af[fm], bb[fn], acc[fm][fn], 0, 0, 0);
    }
  }
#pragma unroll
  for (int fn = 0; fn < 4; ++fn) {
    const int col = n0 + wn * 64 + fn * 16 + lr;
    const float bias = b1[exp * F_DIM + col];
#pragma unroll
    for (int fm = 0; fm < 4; ++fm) {
      const int rbase = m0 + wm * 64 + fm * 16 + lg * 4;
#pragma unroll
      for (int i = 0; i < 4; ++i) {
        const float v = acc[fm][fn][i] + bias;
        const float g = 0.5f * v * (1.f + erff(v * 0.70710678118f));
        hbuf[(size_t)(rbase + i) * F_DIM + col] = f2bf(g);
      }
    }
  }
}

__global__ __launch_bounds__(256) void gemm2_k(
    const unsigned short* __restrict__ hbuf, const float* __restrict__ w2,
    const float* __restrict__ b2, const int* __restrict__ meta,
    const int* __restrict__ slot_token, const float* __restrict__ slot_score,
    float* __restrict__ out) {
  __shared__ unsigned short Al[BM * LDT];
  __shared__ unsigned short Bl[128 * LDT];
  const int m0 = blockIdx.x * BM;
  const int total = meta[16];
  if (m0 >= total) return;
  int exp = 0;
#pragma unroll
  for (int e = 1; e < E_NUM; ++e) if (m0 >= meta[8 + e]) exp = e;
  const int n0 = blockIdx.y * 128;
  const int t = threadIdx.x;
  const int w = t >> 6, l = t & 63;
  const int wm = w >> 1, wn = w & 1;
  const int lr = l & 15, lg = l >> 4;
  const f32x4 fzero = {0.f, 0.f, 0.f, 0.f};
  f32x4 acc[4][4];
#pragma unroll
  for (int a = 0; a < 4; ++a)
#pragma unroll
    for (int b = 0; b < 4; ++b) acc[a][b] = fzero;
  const int ar = t >> 1, ah = t & 1;
  const unsigned short* hrow = hbuf + (size_t)(m0 + ar) * F_DIM + ah * 32;
  const size_t wbase = (size_t)exp * F_DIM * H_DIM;
  const int cg4 = (t & 31) * 4;
  const int kg0 = t >> 5;
  for (int kt = 0; kt < F_DIM / BK; ++kt) {
    const int k0 = kt * BK;
    __syncthreads();
#pragma unroll
    for (int i = 0; i < 4; ++i) {
      *(int4*)&Al[ar * LDT + ah * 32 + i * 8] = *(const int4*)(hrow + k0 + i * 8);
    }
#pragma unroll
    for (int half = 0; half < 2; ++half) {
      const int kg = kg0 + half * 8;
      const float* wp = w2 + wbase + (size_t)(k0 + kg * 4) * H_DIM + n0 + cg4;
      f32x4 r0 = *(const f32x4*)(wp);
      f32x4 r1 = *(const f32x4*)(wp + H_DIM);
      f32x4 r2 = *(const f32x4*)(wp + 2 * H_DIM);
      f32x4 r3 = *(const f32x4*)(wp + 3 * H_DIM);
#pragma unroll
      for (int cc = 0; cc < 4; ++cc) {
        ushort4 u;
        u.x = f2bf(r0[cc]); u.y = f2bf(r1[cc]); u.z = f2bf(r2[cc]); u.w = f2bf(r3[cc]);
        *(ushort4*)&Bl[(cg4 + cc) * LDT + kg * 4] = u;
      }
    }
    __syncthreads();
#pragma unroll
    for (int kk = 0; kk < 2; ++kk) {
      s16x8 af[4], bb[4];
#pragma unroll
      for (int fm = 0; fm < 4; ++fm)
        af[fm] = *(const s16x8*)&Al[(wm * 64 + fm * 16 + lr) * LDT + kk * 32 + lg * 8];
#pragma unroll
      for (int fn = 0; fn < 4; ++fn)
        bb[fn] = *(const s16x8*)&Bl[(wn * 64 + fn * 16 + lr) * LDT + kk * 32 + lg * 8];
#pragma unroll
      for (int fm = 0; fm < 4; ++fm)
#pragma unroll
        for (int fn = 0; fn < 4; ++fn)
          acc[fm][fn] = __builtin_amdgcn_mfma_f32_16x16x32_bf16(af[fm], bb[fn], acc[fm][fn], 0, 0, 0);
    }
  }
#pragma unroll
  for (int fm = 0; fm < 4; ++fm) {
    const int rbase = m0 + wm * 64 + fm * 16 + lg * 4;
    int toks[4]; float ss[4];
#pragma unroll
    for (int i = 0; i < 4; ++i) {
      toks[i] = slot_token[rbase + i];
      ss[i] = slot_score[rbase + i];
    }
#pragma unroll
    for (int fn = 0; fn < 4; ++fn) {
      const int col = n0 + wn * 64 + fn * 16 + lr;
      const float b2v = b2[exp * H_DIM + col];
#pragma unroll
      for (int i = 0; i < 4; ++i) {
        if (toks[i] >= 0)
          atomicAdd(out + (size_t)toks[i] * H_DIM + col, ss[i] * (acc[fm][fn][i] + b2v));
      }
    }
  }
}

extern "C" void kernel_launch(void* const* d_in, const int* in_sizes, int n_in,
                              void* d_out, int out_size, void* d_ws, size_t ws_size,
                              hipStream_t stream) {
  const float* x  = (const float*)d_in[0];
  const float* rw = (const float*)d_in[1];
  const float* w1 = (const float*)d_in[2];
  const float* b1 = (const float*)d_in[3];
  const float* w2 = (const float*)d_in[4];
  const float* b2 = (const float*)d_in[5];
  float* out = (float*)d_out;
  char* ws = (char*)d_ws;

  int*   meta       = (int*)ws;
  int*   topk_e     = (int*)(ws + 4096);
  float* topk_s     = (float*)(ws + 20480);
  int*   slot_token = (int*)(ws + 36864);
  float* slot_score = (float*)(ws + 57344);
  unsigned short* xb   = (unsigned short*)(ws + (1ull << 20));
  unsigned short* hbuf = (unsigned short*)(ws + (6ull << 20));
  unsigned short* wt   = (unsigned short*)(ws + (48ull << 20));
  const size_t NEED = (48ull << 20) + (size_t)E_NUM * H_DIM * F_DIM * 2;

  hipMemsetAsync(meta, 0, 256, stream);
  hipMemsetAsync(out, 0, (size_t)N_TOK * H_DIM * sizeof(float), stream);

  router_k<<<N_TOK, 64, 0, stream>>>(x, rw, meta, topk_e, topk_s);
  scatter_k<<<1, 256, 0, stream>>>(meta, topk_e, topk_s, slot_token, slot_score);

  if (ws_size >= NEED) {
    cvtx_k<<<N_TOK * H_DIM / (256 * 8), 256, 0, stream>>>(x, xb);
    tcvt_k<<<dim3(F_DIM / 64, H_DIM / 64, E_NUM), 256, 0, stream>>>(w1, wt, H_DIM, F_DIM);
    gemm1_f<<<MAX_MT * 32, 256, 0, stream>>>(xb, wt, b1, meta, slot_token, hbuf);
    tcvt_k<<<dim3(H_DIM / 64, F_DIM / 64, E_NUM), 256, 0, stream>>>(w2, wt, F_DIM, H_DIM);
    gemm2_f<<<MAX_MT * 16, 256, 0, stream>>>(hbuf, wt, b2, meta, slot_token, slot_score, out);
  } else {
    gemm1_k<<<dim3(MAX_MT, F_DIM / 128), 256, 0, stream>>>(x, w1, b1, meta, slot_token, hbuf);
    gemm2_k<<<dim3(MAX_MT, H_DIM / 128), 256, 0, stream>>>(hbuf, w2, b2, meta, slot_token, slot_score, out);
  }
}

// Round 3
// 281.452 us; speedup vs baseline: 1.5723x; 1.0863x over previous
//
#include <hip/hip_runtime.h>
#include <cmath>

// GPTNeoXRoutedMLP: N=2048 tokens, H=1024, F=4096, E=8, topk=2.
// R3: 2-phase double-buffered GEMMs (prefetch-before-compute, one barrier/K-step),
// prep fusion (w1-transpose + x-cvt + router in one launch; w2-transpose fused
// as tail blocks of gemm1), tanh-form GELU.

#define H_DIM 1024
#define F_DIM 4096
#define E_NUM 8
#define N_TOK 2048
#define BK 64
#define MAX_SLOTS 5120
#define MAX_MT (MAX_SLOTS / 128)   // 40 row tiles

typedef short s16x8 __attribute__((ext_vector_type(8)));
typedef float f32x4 __attribute__((ext_vector_type(4)));

__device__ __forceinline__ unsigned short f2bf(float f) {
  unsigned int u = __float_as_uint(f);
  u += 0x7fffu + ((u >> 16) & 1u);   // RNE
  return (unsigned short)(u >> 16);
}

__device__ __forceinline__ void gload_lds16(const void* g, void* l) {
  __builtin_amdgcn_global_load_lds(
      (const __attribute__((address_space(1))) unsigned int*)g,
      (__attribute__((address_space(3))) unsigned int*)l, 16, 0, 0);
}

__device__ __forceinline__ int xcd_swz(int orig, int nwg) {
  const int cpx = nwg >> 3;   // nwg is a multiple of 8 (1280 / 640)
  return (orig & 7) * cpx + (orig >> 3);
}

__device__ __forceinline__ float fast_gelu(float v) {
  // tanh-form GELU == v * sigmoid(1.59576912(v + 0.044715 v^3)); |err vs erf-GELU| < 4e-4
  const float w = v * (1.0f + 0.044715f * v * v);
  const float t = __expf(-1.5957691216f * w);
  return v / (1.0f + t);
}

// transpose-convert one 64x64 tile: in [E][R][C] f32 -> out [E][C][R] bf16
__device__ __forceinline__ void tcvt_tile(const float* __restrict__ in,
                                          unsigned short* __restrict__ out,
                                          int R, int C, int tile, float (*T)[65]) {
  const int ctiles = C >> 6;
  const int per_e = ctiles * (R >> 6);
  const int e = tile / per_e;
  const int rem = tile - e * per_e;
  const int r0 = (rem / ctiles) << 6;
  const int c0 = (rem % ctiles) << 6;
  const size_t eb = (size_t)e * R * C;
  in += eb; out += eb;
  const int t = threadIdx.x;
  const int cb = (t & 15) * 4;
#pragma unroll
  for (int it = 0; it < 4; ++it) {
    const int rr = (t >> 4) + it * 16;
    f32x4 v = *(const f32x4*)(in + (size_t)(r0 + rr) * C + c0 + cb);
#pragma unroll
    for (int c = 0; c < 4; ++c) T[rr][cb + c] = v[c];
  }
  __syncthreads();
  const int cc = t >> 2;
  const int rb = (t & 3) * 16;
#pragma unroll
  for (int half = 0; half < 2; ++half) {
    s16x8 u;
#pragma unroll
    for (int j = 0; j < 8; ++j) u[j] = (short)f2bf(T[rb + half * 8 + j][cc]);
    *(s16x8*)&out[(size_t)(c0 + cc) * R + r0 + rb + half * 8] = u;
  }
}

// ---------------- prep1: w1 transpose (8192 blk) | x cvt (1024 blk) | router (512 blk) ----------------
__global__ __launch_bounds__(256) void prep1_k(
    const float* __restrict__ w1, unsigned short* __restrict__ wt1,
    const float* __restrict__ x, unsigned short* __restrict__ xb,
    const float* __restrict__ rw, int* __restrict__ meta,
    int* __restrict__ topk_e, float* __restrict__ topk_s) {
  __shared__ float T[64][65];
  const int b = blockIdx.x;
  const int t = threadIdx.x;
  if (b < 8192) {  // w1 [E][H][F] -> wt1 [E][F][H]
    tcvt_tile(w1, wt1, H_DIM, F_DIM, b, T);
    return;
  }
  if (b < 9216) {  // x f32 -> bf16
    const size_t i = (((size_t)(b - 8192)) * 256 + t) * 8;
    f32x4 a = *(const f32x4*)(x + i);
    f32x4 c = *(const f32x4*)(x + i + 4);
    s16x8 u;
#pragma unroll
    for (int j = 0; j < 4; ++j) { u[j] = (short)f2bf(a[j]); u[4 + j] = (short)f2bf(c[j]); }
    *(s16x8*)&xb[i] = u;
    return;
  }
  // router: one token per wave
  const int n = (b - 9216) * 4 + (t >> 6);
  const int l = t & 63;
  float part[E_NUM];
#pragma unroll
  for (int e = 0; e < E_NUM; ++e) part[e] = 0.f;
  const float* xr = x + (size_t)n * H_DIM;
  for (int h = l; h < H_DIM; h += 64) {
    const float xv = xr[h];
    const float* rwr = rw + h * E_NUM;
#pragma unroll
    for (int e = 0; e < E_NUM; ++e) part[e] += xv * rwr[e];
  }
#pragma unroll
  for (int e = 0; e < E_NUM; ++e) {
#pragma unroll
    for (int off = 32; off > 0; off >>= 1) part[e] += __shfl_down(part[e], off);
  }
  if (l == 0) {
    float v0 = -3.4e38f, v1 = -3.4e38f;
    int i0 = 0, i1 = 0;
#pragma unroll
    for (int e = 0; e < E_NUM; ++e) {
      float v = part[e];
      if (v > v0) { v1 = v0; i1 = i0; v0 = v; i0 = e; }   // strict > : lowest index wins ties
      else if (v > v1) { v1 = v; i1 = e; }
    }
    const float e1 = expf(v1 - v0);
    const float inv = 1.f / (1.f + e1);
    topk_e[2 * n] = i0; topk_e[2 * n + 1] = i1;
    topk_s[2 * n] = inv; topk_s[2 * n + 1] = e1 * inv;
    atomicAdd(&meta[i0], 1);
    atomicAdd(&meta[i1], 1);
  }
}

// ---------------- Scatter: padded offsets + permuted slot lists ----------------
__global__ __launch_bounds__(256) void scatter_k(
    int* __restrict__ meta, const int* __restrict__ topk_e,
    const float* __restrict__ topk_s, int* __restrict__ slot_token,
    float* __restrict__ slot_score) {
  __shared__ int soff[9];
  __shared__ int scur[8];
  const int t = threadIdx.x;
  if (t == 0) {
    int acc = 0;
    for (int e = 0; e < E_NUM; ++e) {
      soff[e] = acc;
      meta[8 + e] = acc;
      acc += ((meta[e] + 127) / 128) * 128;
    }
    soff[8] = acc;
    meta[16] = acc;
  }
  if (t < 8) scur[t] = 0;
  __syncthreads();
  for (int i = t; i < MAX_SLOTS; i += 256) slot_token[i] = -1;
  __syncthreads();
  for (int a = t; a < N_TOK * 2; a += 256) {
    const int e = topk_e[a];
    const int pos = atomicAdd(&scur[e], 1);
    const int slot = soff[e] + pos;
    slot_token[slot] = a >> 1;
    slot_score[slot] = topk_s[a];
  }
}

// ============ GEMM1 (+ fused w2 transpose tail blocks) ============
// h = gelu(xb[gather] @ w1t^T + b1) -> bf16 hbuf. 128x128x64 dbuf 2-phase.
__global__ __launch_bounds__(256, 2) void gemm1_f(
    const unsigned short* __restrict__ xb, const unsigned short* __restrict__ w1t,
    const float* __restrict__ b1, const int* __restrict__ meta,
    const int* __restrict__ slot_token, unsigned short* __restrict__ hbuf,
    const float* __restrict__ w2, unsigned short* __restrict__ wt2) {
  __shared__ __align__(16) char lraw[65536];
  if (blockIdx.x >= MAX_MT * 32) {   // fused: w2 [E][F][H] -> wt2 [E][H][F]
    tcvt_tile(w2, wt2, F_DIM, H_DIM, blockIdx.x - MAX_MT * 32, (float(*)[65])lraw);
    return;
  }
  unsigned short* Al = (unsigned short*)lraw;              // [2][128*64]
  unsigned short* Bl = (unsigned short*)(lraw + 32768);    // [2][128*64]
  const int total = meta[16];
  const int wgid = xcd_swz(blockIdx.x, MAX_MT * 32);
  const int mt = wgid >> 5, nt = wgid & 31;
  const int m0 = mt * 128;
  if (m0 >= total) return;
  int exp = 0;
#pragma unroll
  for (int e = 1; e < E_NUM; ++e) if (m0 >= meta[8 + e]) exp = e;
  const int n0 = nt * 128;
  const int t = threadIdx.x, w = t >> 6, l = t & 63;
  const int wm = w >> 1, wn = w & 1, lr = l & 15, lg = l >> 4;
  const int sr = l >> 3, sc = l & 7;

  const unsigned short* srcA[4];
  const unsigned short* srcB[4];
#pragma unroll
  for (int i = 0; i < 4; ++i) {
    const int r = (w * 4 + i) * 8 + sr;
    const int cd = sc ^ sr;            // pre-swizzled source chunk (r&7 == sr)
    int tk = slot_token[m0 + r]; if (tk < 0) tk = 0;
    srcA[i] = xb + (size_t)tk * H_DIM + cd * 8;
    srcB[i] = w1t + ((size_t)exp * F_DIM + n0 + r) * H_DIM + cd * 8;
  }

  const f32x4 fzero = {0.f, 0.f, 0.f, 0.f};
  f32x4 acc[4][4];
#pragma unroll
  for (int a = 0; a < 4; ++a)
#pragma unroll
    for (int b = 0; b < 4; ++b) acc[a][b] = fzero;

  // prologue: stage tile 0 into buf 0
#pragma unroll
  for (int i = 0; i < 4; ++i) {
    gload_lds16(srcA[i], Al + (w * 4 + i) * 512);
    gload_lds16(srcB[i], Bl + (w * 4 + i) * 512);
  }
  __syncthreads();
  int cur = 0;
  for (int kt = 0; kt < H_DIM / BK; ++kt) {
    const int nxt = cur ^ 1;
    if (kt + 1 < H_DIM / BK) {       // prefetch next tile while computing current
      const int k0 = (kt + 1) * BK;
#pragma unroll
      for (int i = 0; i < 4; ++i) {
        gload_lds16(srcA[i] + k0, Al + nxt * 8192 + (w * 4 + i) * 512);
        gload_lds16(srcB[i] + k0, Bl + nxt * 8192 + (w * 4 + i) * 512);
      }
    }
    const unsigned short* Ac = Al + cur * 8192;
    const unsigned short* Bc = Bl + cur * 8192;
#pragma unroll
    for (int kk = 0; kk < 2; ++kk) {
      s16x8 af[4], bb[4];
#pragma unroll
      for (int fm = 0; fm < 4; ++fm) {
        const int row = wm * 64 + fm * 16 + lr;
        af[fm] = *(const s16x8*)&Ac[row * 64 + (((kk * 4 + lg) ^ (lr & 7)) * 8)];
      }
#pragma unroll
      for (int fn = 0; fn < 4; ++fn) {
        const int row = wn * 64 + fn * 16 + lr;
        bb[fn] = *(const s16x8*)&Bc[row * 64 + (((kk * 4 + lg) ^ (lr & 7)) * 8)];
      }
#pragma unroll
      for (int fm = 0; fm < 4; ++fm)
#pragma unroll
        for (int fn = 0; fn < 4; ++fn)
          acc[fm][fn] = __builtin_amdgcn_mfma_f32_16x16x32_bf16(af[fm], bb[fn], acc[fm][fn], 0, 0, 0);
    }
    __syncthreads();   // vmcnt(0)+lgkmcnt(0)+barrier: next buf ready, cur buf free
    cur = nxt;
  }
#pragma unroll
  for (int fn = 0; fn < 4; ++fn) {
    const int col = n0 + wn * 64 + fn * 16 + lr;
    const float bias = b1[exp * F_DIM + col];
#pragma unroll
    for (int fm = 0; fm < 4; ++fm) {
      const int rbase = m0 + wm * 64 + fm * 16 + lg * 4;
#pragma unroll
      for (int i = 0; i < 4; ++i) {
        hbuf[(size_t)(rbase + i) * F_DIM + col] = f2bf(fast_gelu(acc[fm][fn][i] + bias));
      }
    }
  }
}

// ============ GEMM2: out[token] += s*(hbuf @ w2t^T + b2), 128x64x64 dbuf ============
__global__ __launch_bounds__(256, 2) void gemm2_f(
    const unsigned short* __restrict__ hbuf, const unsigned short* __restrict__ w2t,
    const float* __restrict__ b2, const int* __restrict__ meta,
    const int* __restrict__ slot_token, const float* __restrict__ slot_score,
    float* __restrict__ out) {
  __shared__ __align__(16) char lraw[49152];
  unsigned short* Al = (unsigned short*)lraw;              // [2][128*64]
  unsigned short* Bl = (unsigned short*)(lraw + 32768);    // [2][64*64]
  const int total = meta[16];
  const int wgid = xcd_swz(blockIdx.x, MAX_MT * 16);
  const int mt = wgid >> 4, nt = wgid & 15;
  const int m0 = mt * 128;
  if (m0 >= total) return;
  int exp = 0;
#pragma unroll
  for (int e = 1; e < E_NUM; ++e) if (m0 >= meta[8 + e]) exp = e;
  const int n0 = nt * 64;
  const int t = threadIdx.x, w = t >> 6, l = t & 63;
  const int wm = w >> 1, wn = w & 1, lr = l & 15, lg = l >> 4;
  const int sr = l >> 3, sc = l & 7;

  const unsigned short* srcA[4];
  const unsigned short* srcB[2];
#pragma unroll
  for (int i = 0; i < 4; ++i) {
    const int r = (w * 4 + i) * 8 + sr;
    srcA[i] = hbuf + (size_t)(m0 + r) * F_DIM + (sc ^ sr) * 8;
  }
#pragma unroll
  for (int i = 0; i < 2; ++i) {
    const int r = (w * 2 + i) * 8 + sr;
    srcB[i] = w2t + ((size_t)exp * H_DIM + n0 + r) * F_DIM + (sc ^ sr) * 8;
  }

  const f32x4 fzero = {0.f, 0.f, 0.f, 0.f};
  f32x4 acc[4][2];
#pragma unroll
  for (int a = 0; a < 4; ++a)
#pragma unroll
    for (int b = 0; b < 2; ++b) acc[a][b] = fzero;

  // prologue
#pragma unroll
  for (int i = 0; i < 4; ++i) gload_lds16(srcA[i], Al + (w * 4 + i) * 512);
#pragma unroll
  for (int i = 0; i < 2; ++i) gload_lds16(srcB[i], Bl + (w * 2 + i) * 512);
  __syncthreads();
  int cur = 0;
  for (int kt = 0; kt < F_DIM / BK; ++kt) {
    const int nxt = cur ^ 1;
    if (kt + 1 < F_DIM / BK) {
      const int k0 = (kt + 1) * BK;
#pragma unroll
      for (int i = 0; i < 4; ++i)
        gload_lds16(srcA[i] + k0, Al + nxt * 8192 + (w * 4 + i) * 512);
#pragma unroll
      for (int i = 0; i < 2; ++i)
        gload_lds16(srcB[i] + k0, Bl + nxt * 4096 + (w * 2 + i) * 512);
    }
    const unsigned short* Ac = Al + cur * 8192;
    const unsigned short* Bc = Bl + cur * 4096;
#pragma unroll
    for (int kk = 0; kk < 2; ++kk) {
      s16x8 af[4], bb[2];
#pragma unroll
      for (int fm = 0; fm < 4; ++fm) {
        const int row = wm * 64 + fm * 16 + lr;
        af[fm] = *(const s16x8*)&Ac[row * 64 + (((kk * 4 + lg) ^ (lr & 7)) * 8)];
      }
#pragma unroll
      for (int fn = 0; fn < 2; ++fn) {
        const int row = wn * 32 + fn * 16 + lr;
        bb[fn] = *(const s16x8*)&Bc[row * 64 + (((kk * 4 + lg) ^ (lr & 7)) * 8)];
      }
#pragma unroll
      for (int fm = 0; fm < 4; ++fm)
#pragma unroll
        for (int fn = 0; fn < 2; ++fn)
          acc[fm][fn] = __builtin_amdgcn_mfma_f32_16x16x32_bf16(af[fm], bb[fn], acc[fm][fn], 0, 0, 0);
    }
    __syncthreads();
    cur = nxt;
  }
#pragma unroll
  for (int fm = 0; fm < 4; ++fm) {
    const int rbase = m0 + wm * 64 + fm * 16 + lg * 4;
    int toks[4]; float ss[4];
#pragma unroll
    for (int i = 0; i < 4; ++i) {
      toks[i] = slot_token[rbase + i];
      ss[i] = slot_score[rbase + i];
    }
#pragma unroll
    for (int fn = 0; fn < 2; ++fn) {
      const int col = n0 + wn * 32 + fn * 16 + lr;
      const float b2v = b2[exp * H_DIM + col];
#pragma unroll
      for (int i = 0; i < 4; ++i) {
        if (toks[i] >= 0)
          atomicAdd(out + (size_t)toks[i] * H_DIM + col, ss[i] * (acc[fm][fn][i] + b2v));
      }
    }
  }
}

// standalone w2 transpose for the (ws too small) sequential path
__global__ __launch_bounds__(256) void tcvt2_k(const float* __restrict__ in,
                                               unsigned short* __restrict__ out) {
  __shared__ float T[64][65];
  tcvt_tile(in, out, F_DIM, H_DIM, blockIdx.x, T);
}

extern "C" void kernel_launch(void* const* d_in, const int* in_sizes, int n_in,
                              void* d_out, int out_size, void* d_ws, size_t ws_size,
                              hipStream_t stream) {
  const float* x  = (const float*)d_in[0];
  const float* rw = (const float*)d_in[1];
  const float* w1 = (const float*)d_in[2];
  const float* b1 = (const float*)d_in[3];
  const float* w2 = (const float*)d_in[4];
  const float* b2 = (const float*)d_in[5];
  float* out = (float*)d_out;
  char* ws = (char*)d_ws;

  int*   meta       = (int*)ws;
  int*   topk_e     = (int*)(ws + 4096);
  float* topk_s     = (float*)(ws + 20480);
  int*   slot_token = (int*)(ws + 36864);
  float* slot_score = (float*)(ws + 57344);
  unsigned short* xb   = (unsigned short*)(ws + (1ull << 20));
  unsigned short* hbuf = (unsigned short*)(ws + (6ull << 20));
  unsigned short* wt1  = (unsigned short*)(ws + (48ull << 20));
  const size_t W = (size_t)E_NUM * H_DIM * F_DIM * 2;   // 64 MiB
  unsigned short* wt2  = (unsigned short*)(ws + (48ull << 20) + W);
  const size_t NEED_FULL = (48ull << 20) + 2 * W;       // 176 MiB
  const bool full = ws_size >= NEED_FULL;

  hipMemsetAsync(meta, 0, 256, stream);
  hipMemsetAsync(out, 0, (size_t)N_TOK * H_DIM * sizeof(float), stream);

  // w1-transpose | x-convert | router, one launch
  prep1_k<<<8192 + 1024 + 512, 256, 0, stream>>>(w1, wt1, x, xb, rw, meta, topk_e, topk_s);
  scatter_k<<<1, 256, 0, stream>>>(meta, topk_e, topk_s, slot_token, slot_score);

  if (full) {
    gemm1_f<<<MAX_MT * 32 + 8192, 256, 0, stream>>>(xb, wt1, b1, meta, slot_token, hbuf, w2, wt2);
    gemm2_f<<<MAX_MT * 16, 256, 0, stream>>>(hbuf, wt2, b2, meta, slot_token, slot_score, out);
  } else {
    gemm1_f<<<MAX_MT * 32, 256, 0, stream>>>(xb, wt1, b1, meta, slot_token, hbuf, w2, wt1);
    tcvt2_k<<<8192, 256, 0, stream>>>(w2, wt1);   // reuse wt1 after gemm1 consumed it
    gemm2_f<<<MAX_MT * 16, 256, 0, stream>>>(hbuf, wt1, b2, meta, slot_token, slot_score, out);
  }
}